// Round 5
// baseline (223.310 us; speedup 1.0000x reference)
//
#include <hip/hip_runtime.h>

#define N_NODES 4096
#define FIN     512
#define FOUT    256
#define NSPLIT  4
#define NTILES  ((N_NODES / NSPLIT) / 64)   // 16

typedef __attribute__((ext_vector_type(8))) short bf16x8s;
typedef __attribute__((ext_vector_type(4))) float f32x4;
typedef __attribute__((ext_vector_type(8))) unsigned short u16x8;
typedef unsigned short u16;
typedef unsigned int   u32;
typedef unsigned long long u64;

__device__ inline u16 f2b(float f) {
    union { float f; unsigned int u; } v; v.f = f;
    unsigned int r = v.u + 0x7fffu + ((v.u >> 16) & 1u);   // RTNE
    return (u16)(r >> 16);
}

// ---------------------------------------------------------------------------
// prep: [0,1024)    h fp32 -> hb bf16
//       [1024,3072) adj -> bitmask. Lane-contiguous int4 loads (16B/lane,
//                   16 lines/instr) + LDS nibble transpose; layout identical
//                   to previous rounds (bit i of u32 word w = adj[32w+i]).
//       [3072,3136) W_b -> WTb bf16 transposed [n][k]
//       [3136]      zero s1/s2
// ---------------------------------------------------------------------------
__global__ __launch_bounds__(256) void prep_kernel(
    const float* __restrict__ h, const float* __restrict__ Wn,
    const float* __restrict__ Wd,
    const int* __restrict__ adjn, const int* __restrict__ adjd,
    u16* __restrict__ hb, u16* __restrict__ WTb, u32* __restrict__ bits32,
    float* __restrict__ s12)
{
    __shared__ u16 tl[64 * 72];
    __shared__ u32 nib_lds[2 * 256];
    const int t = threadIdx.x;
    const int bid = blockIdx.x;

    if (bid < 1024) {                       // h convert
        int idx = (bid * 256 + t) * 8;
        float4 f0 = *(const float4*)&h[idx];
        float4 f1 = *(const float4*)&h[idx + 4];
        u16x8 o;
        o[0]=f2b(f0.x); o[1]=f2b(f0.y); o[2]=f2b(f0.z); o[3]=f2b(f0.w);
        o[4]=f2b(f1.x); o[5]=f2b(f1.y); o[6]=f2b(f1.z); o[7]=f2b(f1.w);
        *(u16x8*)&hb[idx] = o;
    } else if (bid < 3072) {                // adj -> bits
        const int a = bid - 1024;           // 0..2047
        #pragma unroll
        for (int s = 0; s < 2; ++s) {
            const int g = a * 2 + s;        // chunk of 8192 ints
            const int* p = (g < 2048) ? (adjn + (size_t)g * 8192)
                                      : (adjd + (size_t)(g - 2048) * 8192);
            const int4* src = (const int4*)p;
            int4 v[8];
            #pragma unroll
            for (int j = 0; j < 8; ++j) v[j] = src[j * 256 + t];   // lane-contiguous
            u32 nibs = 0;
            #pragma unroll
            for (int j = 0; j < 8; ++j) {
                u32 nb = (u32)(v[j].x > 0) | ((u32)(v[j].y > 0) << 1)
                       | ((u32)(v[j].z > 0) << 2) | ((u32)(v[j].w > 0) << 3);
                nibs |= nb << (4 * j);
            }
            u32* nbuf = nib_lds + s * 256;
            // thread t holds nibble j (load-group j) for ints [j*1024+4t, +4).
            // store swizzled: slot u=t at ((u&7)<<5)|(u>>3) -> reads conflict-free
            nbuf[((t & 7) << 5) | (t >> 3)] = nibs;
            __syncthreads();
            // assemble out u32 covering ints [32t, 32t+32): group j = t>>5,
            // nibbles from slots u0..u0+7, u0 = 8*(t&31); swizzled addr = (r<<5)|(t&31)
            const int j = t >> 5;
            u32 outw = 0;
            #pragma unroll
            for (int r = 0; r < 8; ++r) {
                u32 nv = nbuf[(r << 5) | (t & 31)];
                outw |= ((nv >> (4 * j)) & 0xFu) << (4 * r);
            }
            bits32[(size_t)g * 256 + t] = outw;
        }
    } else if (bid < 3136) {                // W transpose+convert, 64x64 tiles
        int id = bid - 3072;
        int kx = id & 7, ny = (id >> 3) & 3, b = id >> 5;
        const float* W = b ? Wd : Wn;
        int k0 = kx * 64, n0 = ny * 64;
        int kr = t >> 2, nc0 = (t & 3) * 16;
        const float* src = W + (size_t)(k0 + kr) * FOUT + n0 + nc0;
        #pragma unroll
        for (int jv = 0; jv < 4; ++jv) {
            float4 f = *(const float4*)(src + jv * 4);
            tl[(nc0 + jv * 4 + 0) * 72 + kr] = f2b(f.x);
            tl[(nc0 + jv * 4 + 1) * 72 + kr] = f2b(f.y);
            tl[(nc0 + jv * 4 + 2) * 72 + kr] = f2b(f.z);
            tl[(nc0 + jv * 4 + 3) * 72 + kr] = f2b(f.w);
        }
        __syncthreads();
        int n = t >> 2, kc0 = (t & 3) * 16;
        u16* dst = WTb + ((size_t)b << 17) + (size_t)(n0 + n) * FIN + k0 + kc0;
        *(uint4*)dst       = *(uint4*)&tl[n * 72 + kc0];
        *(uint4*)(dst + 8) = *(uint4*)&tl[n * 72 + kc0 + 8];
    } else {                                // zero s1,s2 (16384 floats)
        float4 z = {0.f, 0.f, 0.f, 0.f};
        float4* p4 = (float4*)s12;
        #pragma unroll
        for (int k = 0; k < 16; ++k) p4[k * 256 + t] = z;
    }
}

// ---------------------------------------------------------------------------
// wh_gemm: WhT[b][n][i] = (hb @ W_b)[i][n]; epilogue also accumulates
// s1[b][i] += sum_n C[i][n]*a1[n], s2 likewise (atomics across n0-blocks).
// grid (64, 4, 2).
// ---------------------------------------------------------------------------
__global__ __launch_bounds__(256) void wh_gemm_kernel(
    const u16* __restrict__ hb, const u16* __restrict__ WTb,
    const float* __restrict__ a1n, const float* __restrict__ a2n,
    const float* __restrict__ a1d, const float* __restrict__ a2d,
    u16* __restrict__ WhT, float* __restrict__ s1, float* __restrict__ s2)
{
    __shared__ u16 smem[8192];
    u16* a_lds = smem;
    u16* b_lds = smem + 4096;

    const int t = threadIdx.x, lane = t & 63, w = t >> 6;
    const int q = lane >> 4, ln = lane & 15;
    const int i0 = blockIdx.x * 64, n0 = blockIdx.y * 64, b = blockIdx.z;
    const u16* wt = WTb + ((size_t)b << 17);

    f32x4 acc[4];
    #pragma unroll
    for (int i = 0; i < 4; ++i) acc[i] = (f32x4){0.f, 0.f, 0.f, 0.f};

    for (int kt = 0; kt < 8; ++kt) {
        const int k0 = kt * 64;
        __syncthreads();
        #pragma unroll
        for (int it = 0; it < 2; ++it) {
            int chunk = it * 256 + t;
            int r = chunk >> 3, kc = chunk & 7;
            const u16* g = hb + (size_t)(i0 + r) * FIN + k0 + ((kc ^ (r & 7)) * 8);
            u16* l = a_lds + (it * 256 + w * 64) * 8;
            __builtin_amdgcn_global_load_lds(
                (const __attribute__((address_space(1))) void*)g,
                (__attribute__((address_space(3))) void*)l, 16, 0, 0);
        }
        #pragma unroll
        for (int it = 0; it < 2; ++it) {
            int chunk = it * 256 + t;
            int n = chunk >> 3, kc = chunk & 7;
            const u16* g = wt + (size_t)(n0 + n) * FIN + k0 + ((kc ^ (n & 7)) * 8);
            u16* l = b_lds + (it * 256 + w * 64) * 8;
            __builtin_amdgcn_global_load_lds(
                (const __attribute__((address_space(1))) void*)g,
                (__attribute__((address_space(3))) void*)l, 16, 0, 0);
        }
        __syncthreads();
        #pragma unroll
        for (int ks = 0; ks < 2; ++ks) {
            int sw = ((ks * 4 + q) ^ (ln & 7)) * 8;
            bf16x8s af = *(const bf16x8s*)&a_lds[(w * 16 + ln) * 64 + sw];
            #pragma unroll
            for (int nt = 0; nt < 4; ++nt) {
                bf16x8s bfv = *(const bf16x8s*)&b_lds[(nt * 16 + ln) * 64 + sw];
                acc[nt] = __builtin_amdgcn_mfma_f32_16x16x32_bf16(af, bfv, acc[nt], 0, 0, 0);
            }
        }
    }

    {
        const float* a1 = b ? a1d : a1n;
        const float* a2 = b ? a2d : a2n;
        float s1p[4] = {0.f, 0.f, 0.f, 0.f};
        float s2p[4] = {0.f, 0.f, 0.f, 0.f};
        #pragma unroll
        for (int nt = 0; nt < 4; ++nt) {
            float va1 = a1[n0 + nt * 16 + ln];
            float va2 = a2[n0 + nt * 16 + ln];
            #pragma unroll
            for (int r = 0; r < 4; ++r) {
                s1p[r] += acc[nt][r] * va1;
                s2p[r] += acc[nt][r] * va2;
            }
        }
        #pragma unroll
        for (int r = 0; r < 4; ++r) {
            #pragma unroll
            for (int off = 8; off >= 1; off >>= 1) {
                s1p[r] += __shfl_xor(s1p[r], off);
                s2p[r] += __shfl_xor(s2p[r], off);
            }
            if (ln == 0) {
                int row = i0 + w * 16 + q * 4 + r;
                atomicAdd(&s1[b * N_NODES + row], s1p[r]);
                atomicAdd(&s2[b * N_NODES + row], s2p[r]);
            }
        }
    }

    __syncthreads();
    #pragma unroll
    for (int nt = 0; nt < 4; ++nt)
        #pragma unroll
        for (int r = 0; r < 4; ++r)
            smem[(nt * 16 + ln) * 72 + (w * 16 + q * 4 + r)] = f2b(acc[nt][r]);
    __syncthreads();
    {
        const int nl = t >> 2, is = (t & 3) * 16;
        u16* dst = WhT + ((size_t)b << 20) + (size_t)(n0 + nl) * N_NODES + i0 + is;
        *(uint4*)dst       = *(uint4*)&smem[nl * 72 + is];
        *(uint4*)(dst + 8) = *(uint4*)&smem[nl * 72 + is + 8];
    }
}

// ---------------------------------------------------------------------------
// attn: 64 rows x 1024-j per block; bits from L2; bits/s2 prefetched a tile
// ahead. grid (64, NSPLIT, 2).
// ---------------------------------------------------------------------------
__global__ __launch_bounds__(256) void attn_kernel(
    const u32* __restrict__ bits,
    const u16* __restrict__ WhT,
    const float* __restrict__ s1, const float* __restrict__ s2,
    float* __restrict__ num_ws, float* __restrict__ den_ws)
{
    __shared__ u16 wht_lds[256 * 64];   // swizzled [n][kchunk^(n&7)], 32 KB
    __shared__ u16 p_lds[64 * 64];      // swizzled, 8 KB
    __shared__ float den_lds[64];

    const int t = threadIdx.x, lane = t & 63, w = t >> 6;
    const int q = lane >> 4, ln = lane & 15;
    const int b = blockIdx.z, split = blockIdx.y;
    const int i0 = blockIdx.x * 64;

    const u16* whtB = WhT + ((size_t)b << 20);
    const float* s1b = s1 + b * N_NODES;
    const float* s2b = s2 + b * N_NODES;

    const int pr = t >> 3;              // P row 0..31 (also handles pr+32)
    const int cw = t & 7;               // P k-chunk 0..7
    const int pc = cw * 8;
    const int bsh = (cw & 3) * 8;
    const float s1v0 = s1b[i0 + pr];
    const float s1v1 = s1b[i0 + pr + 32];
    const u32* bitrow0 = bits + (size_t)b * (N_NODES * (N_NODES / 32))
                              + (size_t)(i0 + pr) * (N_NODES / 32) + (cw >> 2);
    const u32* bitrow1 = bitrow0 + 32 * (N_NODES / 32);

    if (t < 64) den_lds[t] = 0.f;

    f32x4 acc[4][4];
    #pragma unroll
    for (int mt = 0; mt < 4; ++mt)
        #pragma unroll
        for (int nt = 0; nt < 4; ++nt) acc[mt][nt] = (f32x4){0.f, 0.f, 0.f, 0.f};

    const int jbase = split * (N_NODES / NSPLIT);
    u32 bw0_pf = bitrow0[jbase >> 5];
    u32 bw1_pf = bitrow1[jbase >> 5];
    float4 sv0_pf = *(const float4*)&s2b[jbase + pc];
    float4 sv1_pf = *(const float4*)&s2b[jbase + pc + 4];

    for (int jt = 0; jt < NTILES; ++jt) {
        const int j0 = jbase + jt * 64;
        __syncthreads();
        #pragma unroll
        for (int it = 0; it < 8; ++it) {   // stage 256n x 64j WhT tile
            int chunk = it * 256 + t;
            int n = chunk >> 3, kc = chunk & 7;
            const u16* g = whtB + (size_t)n * N_NODES + j0 + ((kc ^ (n & 7)) * 8);
            u16* l = wht_lds + (it * 256 + w * 64) * 8;
            __builtin_amdgcn_global_load_lds(
                (const __attribute__((address_space(1))) void*)g,
                (__attribute__((address_space(3))) void*)l, 16, 0, 0);
        }
        u32 bw0 = bw0_pf, bw1 = bw1_pf;
        float4 sv0 = sv0_pf, sv1 = sv1_pf;
        if (jt < NTILES - 1) {             // prefetch next tile
            bw0_pf = bitrow0[(j0 + 64) >> 5];
            bw1_pf = bitrow1[(j0 + 64) >> 5];
            sv0_pf = *(const float4*)&s2b[j0 + 64 + pc];
            sv1_pf = *(const float4*)&s2b[j0 + 64 + pc + 4];
        }
        u32 m0 = (bw0 >> bsh) & 0xffu;
        u32 m1 = (bw1 >> bsh) & 0xffu;
        float svf[8] = {sv0.x, sv0.y, sv0.z, sv0.w, sv1.x, sv1.y, sv1.z, sv1.w};
        float d0 = 0.f, d1 = 0.f;
        u16x8 pk0, pk1;
        #pragma unroll
        for (int jj = 0; jj < 8; ++jj) {
            float sv = svf[jj];
            float x0 = s1v0 + sv, x1 = s1v1 + sv;
            float p0 = ((m0 >> jj) & 1u) ? __expf(fmaxf(x0, 0.2f * x0)) : 0.f;
            float p1 = ((m1 >> jj) & 1u) ? __expf(fmaxf(x1, 0.2f * x1)) : 0.f;
            d0 += p0; d1 += p1;
            pk0[jj] = f2b(p0); pk1[jj] = f2b(p1);
        }
        d0 += __shfl_down(d0, 4, 8); d1 += __shfl_down(d1, 4, 8);
        d0 += __shfl_down(d0, 2, 8); d1 += __shfl_down(d1, 2, 8);
        d0 += __shfl_down(d0, 1, 8); d1 += __shfl_down(d1, 1, 8);
        if ((t & 7) == 0) { den_lds[pr] += d0; den_lds[pr + 32] += d1; }
        int swp = ((cw ^ (pr & 7)) * 8);
        *(u16x8*)&p_lds[pr * 64 + swp] = pk0;
        *(u16x8*)&p_lds[(pr + 32) * 64 + swp] = pk1;
        __syncthreads();
        #pragma unroll
        for (int ks = 0; ks < 2; ++ks) {
            int sw = ((ks * 4 + q) ^ (ln & 7)) * 8;
            bf16x8s af[4];
            #pragma unroll
            for (int mt = 0; mt < 4; ++mt)
                af[mt] = *(const bf16x8s*)&p_lds[(mt * 16 + ln) * 64 + sw];
            #pragma unroll
            for (int nt = 0; nt < 4; ++nt) {
                bf16x8s bfv = *(const bf16x8s*)&wht_lds[(w * 64 + nt * 16 + ln) * 64 + sw];
                #pragma unroll
                for (int mt = 0; mt < 4; ++mt)
                    acc[mt][nt] = __builtin_amdgcn_mfma_f32_16x16x32_bf16(af[mt], bfv, acc[mt][nt], 0, 0, 0);
            }
        }
    }
    const size_t pbase = (size_t)(b * NSPLIT + split) * N_NODES;
    #pragma unroll
    for (int mt = 0; mt < 4; ++mt)
        #pragma unroll
        for (int r = 0; r < 4; ++r) {
            int row = mt * 16 + q * 4 + r;
            #pragma unroll
            for (int nt = 0; nt < 4; ++nt)
                num_ws[(pbase + i0 + row) * FOUT + w * 64 + nt * 16 + ln] = acc[mt][nt][r];
        }
    if (t < 64) den_ws[pbase + i0 + t] = den_lds[t];
}

// ---------------------------------------------------------------------------
// reduce: sum splits, elu(num/den), merge branches.
// ---------------------------------------------------------------------------
__global__ __launch_bounds__(256) void reduce_kernel(
    const float* __restrict__ num_ws, const float* __restrict__ den_ws,
    float* __restrict__ out)
{
    int gid = blockIdx.x * 256 + threadIdx.x;
    int i = gid >> 6;
    int f4 = (gid & 63) * 4;
    float4 o = {0.f, 0.f, 0.f, 0.f};
    #pragma unroll
    for (int b = 0; b < 2; ++b) {
        float4 num = {0.f, 0.f, 0.f, 0.f};
        float den = 0.f;
        #pragma unroll
        for (int s = 0; s < NSPLIT; ++s) {
            const float4 v = *(const float4*)&num_ws[((size_t)(b * NSPLIT + s) * N_NODES + i) * FOUT + f4];
            num.x += v.x; num.y += v.y; num.z += v.z; num.w += v.w;
            den += den_ws[(size_t)(b * NSPLIT + s) * N_NODES + i];
        }
        float inv = 1.0f / den;
        float e0 = num.x * inv, e1 = num.y * inv, e2 = num.z * inv, e3 = num.w * inv;
        o.x += (e0 > 0.f) ? e0 : expm1f(e0);
        o.y += (e1 > 0.f) ? e1 : expm1f(e1);
        o.z += (e2 > 0.f) ? e2 : expm1f(e2);
        o.w += (e3 > 0.f) ? e3 : expm1f(e3);
    }
    *(float4*)&out[(size_t)i * FOUT + f4] = o;
}

extern "C" void kernel_launch(void* const* d_in, const int* in_sizes, int n_in,
                              void* d_out, int out_size, void* d_ws, size_t ws_size,
                              hipStream_t stream) {
    const float* h    = (const float*)d_in[0];
    const int*   adjn = (const int*)d_in[1];
    const int*   adjd = (const int*)d_in[2];
    const float* Wn   = (const float*)d_in[4];
    const float* a1n  = (const float*)d_in[5];
    const float* a2n  = (const float*)d_in[6];
    const float* Wd   = (const float*)d_in[7];
    const float* a1d  = (const float*)d_in[8];
    const float* a2d  = (const float*)d_in[9];

    char* ws = (char*)d_ws;
    // [0,4M): WhT   [4M,8M): bits   [8M,8M+192K): s1,s2,den
    // [8.25M,12.25M): hb   [12.25M,12.75M): WTb   (dead after wh_gemm)
    // [8.25M,40.25M): num  (overlays hb/WTb; written by attn after wh_gemm)
    u16*  WhT  = (u16*)ws;
    u32*  bits = (u32*)(ws + ((size_t)4 << 20));
    float* s1  = (float*)(ws + ((size_t)8 << 20));
    float* s2  = s1 + 2 * N_NODES;
    float* den = s2 + 2 * N_NODES;
    u16*  hb   = (u16*)(ws + ((size_t)8 << 20) + ((size_t)256 << 10));
    u16*  WTb  = (u16*)(ws + ((size_t)12 << 20) + ((size_t)256 << 10));
    float* num = (float*)(ws + ((size_t)8 << 20) + ((size_t)256 << 10));

    prep_kernel<<<3137, 256, 0, stream>>>(h, Wn, Wd, adjn, adjd, hb, WTb, bits, s1);
    wh_gemm_kernel<<<dim3(64, 4, 2), 256, 0, stream>>>(hb, WTb, a1n, a2n, a1d, a2d, WhT, s1, s2);
    attn_kernel<<<dim3(64, NSPLIT, 2), 256, 0, stream>>>(bits, WhT, s1, s2, num, den);
    reduce_kernel<<<1024, 256, 0, stream>>>(num, den, (float*)d_out);
}

// Round 6
// 204.026 us; speedup vs baseline: 1.0945x; 1.0945x over previous
//
#include <hip/hip_runtime.h>

#define N_NODES 4096
#define FIN     512
#define FOUT    256
#define NSPLIT  4
#define NTILES  ((N_NODES / NSPLIT) / 64)   // 16

typedef __attribute__((ext_vector_type(8))) short bf16x8s;
typedef __attribute__((ext_vector_type(4))) float f32x4;
typedef __attribute__((ext_vector_type(8))) unsigned short u16x8;
typedef unsigned short u16;
typedef unsigned int   u32;

__device__ inline u16 f2b(float f) {
    union { float f; unsigned int u; } v; v.f = f;
    unsigned int r = v.u + 0x7fffu + ((v.u >> 16) & 1u);   // RTNE
    return (u16)(r >> 16);
}

// ---------------------------------------------------------------------------
// prep: [0,1024)    h fp32 -> hb bf16
//       [1024,1088) W_b -> WTb bf16 transposed [n][k]
//       [1088]      zero s1/s2
// (adj is consumed directly by attn_kernel — no conversion pass.)
// ---------------------------------------------------------------------------
__global__ __launch_bounds__(256) void prep_kernel(
    const float* __restrict__ h, const float* __restrict__ Wn,
    const float* __restrict__ Wd,
    u16* __restrict__ hb, u16* __restrict__ WTb, float* __restrict__ s12)
{
    __shared__ u16 tl[64 * 72];
    const int t = threadIdx.x;
    const int bid = blockIdx.x;

    if (bid < 1024) {                       // h convert
        int idx = (bid * 256 + t) * 8;
        float4 f0 = *(const float4*)&h[idx];
        float4 f1 = *(const float4*)&h[idx + 4];
        u16x8 o;
        o[0]=f2b(f0.x); o[1]=f2b(f0.y); o[2]=f2b(f0.z); o[3]=f2b(f0.w);
        o[4]=f2b(f1.x); o[5]=f2b(f1.y); o[6]=f2b(f1.z); o[7]=f2b(f1.w);
        *(u16x8*)&hb[idx] = o;
    } else if (bid < 1088) {                // W transpose+convert, 64x64 tiles
        int id = bid - 1024;
        int kx = id & 7, ny = (id >> 3) & 3, b = id >> 5;
        const float* W = b ? Wd : Wn;
        int k0 = kx * 64, n0 = ny * 64;
        int kr = t >> 2, nc0 = (t & 3) * 16;
        const float* src = W + (size_t)(k0 + kr) * FOUT + n0 + nc0;
        #pragma unroll
        for (int jv = 0; jv < 4; ++jv) {
            float4 f = *(const float4*)(src + jv * 4);
            tl[(nc0 + jv * 4 + 0) * 72 + kr] = f2b(f.x);
            tl[(nc0 + jv * 4 + 1) * 72 + kr] = f2b(f.y);
            tl[(nc0 + jv * 4 + 2) * 72 + kr] = f2b(f.z);
            tl[(nc0 + jv * 4 + 3) * 72 + kr] = f2b(f.w);
        }
        __syncthreads();
        int n = t >> 2, kc0 = (t & 3) * 16;
        u16* dst = WTb + ((size_t)b << 17) + (size_t)(n0 + n) * FIN + k0 + kc0;
        *(uint4*)dst       = *(uint4*)&tl[n * 72 + kc0];
        *(uint4*)(dst + 8) = *(uint4*)&tl[n * 72 + kc0 + 8];
    } else {                                // zero s1,s2 (16384 floats)
        float4 z = {0.f, 0.f, 0.f, 0.f};
        float4* p4 = (float4*)s12;
        #pragma unroll
        for (int k = 0; k < 16; ++k) p4[k * 256 + t] = z;
    }
}

// ---------------------------------------------------------------------------
// wh_gemm: WhT[b][n][i] = (hb @ W_b)[i][n]; epilogue also accumulates
// s1[b][i] += sum_n C[i][n]*a1[n], s2 likewise (atomics across n0-blocks).
// grid (64, 4, 2).
// ---------------------------------------------------------------------------
__global__ __launch_bounds__(256) void wh_gemm_kernel(
    const u16* __restrict__ hb, const u16* __restrict__ WTb,
    const float* __restrict__ a1n, const float* __restrict__ a2n,
    const float* __restrict__ a1d, const float* __restrict__ a2d,
    u16* __restrict__ WhT, float* __restrict__ s1, float* __restrict__ s2)
{
    __shared__ u16 smem[8192];
    u16* a_lds = smem;
    u16* b_lds = smem + 4096;

    const int t = threadIdx.x, lane = t & 63, w = t >> 6;
    const int q = lane >> 4, ln = lane & 15;
    const int i0 = blockIdx.x * 64, n0 = blockIdx.y * 64, b = blockIdx.z;
    const u16* wt = WTb + ((size_t)b << 17);

    f32x4 acc[4];
    #pragma unroll
    for (int i = 0; i < 4; ++i) acc[i] = (f32x4){0.f, 0.f, 0.f, 0.f};

    for (int kt = 0; kt < 8; ++kt) {
        const int k0 = kt * 64;
        __syncthreads();
        #pragma unroll
        for (int it = 0; it < 2; ++it) {
            int chunk = it * 256 + t;
            int r = chunk >> 3, kc = chunk & 7;
            const u16* g = hb + (size_t)(i0 + r) * FIN + k0 + ((kc ^ (r & 7)) * 8);
            u16* l = a_lds + (it * 256 + w * 64) * 8;
            __builtin_amdgcn_global_load_lds(
                (const __attribute__((address_space(1))) void*)g,
                (__attribute__((address_space(3))) void*)l, 16, 0, 0);
        }
        #pragma unroll
        for (int it = 0; it < 2; ++it) {
            int chunk = it * 256 + t;
            int n = chunk >> 3, kc = chunk & 7;
            const u16* g = wt + (size_t)(n0 + n) * FIN + k0 + ((kc ^ (n & 7)) * 8);
            u16* l = b_lds + (it * 256 + w * 64) * 8;
            __builtin_amdgcn_global_load_lds(
                (const __attribute__((address_space(1))) void*)g,
                (__attribute__((address_space(3))) void*)l, 16, 0, 0);
        }
        __syncthreads();
        #pragma unroll
        for (int ks = 0; ks < 2; ++ks) {
            int sw = ((ks * 4 + q) ^ (ln & 7)) * 8;
            bf16x8s af = *(const bf16x8s*)&a_lds[(w * 16 + ln) * 64 + sw];
            #pragma unroll
            for (int nt = 0; nt < 4; ++nt) {
                bf16x8s bfv = *(const bf16x8s*)&b_lds[(nt * 16 + ln) * 64 + sw];
                acc[nt] = __builtin_amdgcn_mfma_f32_16x16x32_bf16(af, bfv, acc[nt], 0, 0, 0);
            }
        }
    }

    {
        const float* a1 = b ? a1d : a1n;
        const float* a2 = b ? a2d : a2n;
        float s1p[4] = {0.f, 0.f, 0.f, 0.f};
        float s2p[4] = {0.f, 0.f, 0.f, 0.f};
        #pragma unroll
        for (int nt = 0; nt < 4; ++nt) {
            float va1 = a1[n0 + nt * 16 + ln];
            float va2 = a2[n0 + nt * 16 + ln];
            #pragma unroll
            for (int r = 0; r < 4; ++r) {
                s1p[r] += acc[nt][r] * va1;
                s2p[r] += acc[nt][r] * va2;
            }
        }
        #pragma unroll
        for (int r = 0; r < 4; ++r) {
            #pragma unroll
            for (int off = 8; off >= 1; off >>= 1) {
                s1p[r] += __shfl_xor(s1p[r], off);
                s2p[r] += __shfl_xor(s2p[r], off);
            }
            if (ln == 0) {
                int row = i0 + w * 16 + q * 4 + r;
                atomicAdd(&s1[b * N_NODES + row], s1p[r]);
                atomicAdd(&s2[b * N_NODES + row], s2p[r]);
            }
        }
    }

    __syncthreads();
    #pragma unroll
    for (int nt = 0; nt < 4; ++nt)
        #pragma unroll
        for (int r = 0; r < 4; ++r)
            smem[(nt * 16 + ln) * 72 + (w * 16 + q * 4 + r)] = f2b(acc[nt][r]);
    __syncthreads();
    {
        const int nl = t >> 2, is = (t & 3) * 16;
        u16* dst = WhT + ((size_t)b << 20) + (size_t)(n0 + nl) * N_NODES + i0 + is;
        *(uint4*)dst       = *(uint4*)&smem[nl * 72 + is];
        *(uint4*)(dst + 8) = *(uint4*)&smem[nl * 72 + is + 8];
    }
}

// ---------------------------------------------------------------------------
// attn: 64 rows x 1024-j per block; adj read DIRECTLY (int4, one-tile-ahead
// register prefetch hides HBM latency under the MFMA phase).
// grid (64, NSPLIT, 2).
// ---------------------------------------------------------------------------
__global__ __launch_bounds__(256) void attn_kernel(
    const int* __restrict__ adj_n, const int* __restrict__ adj_d,
    const u16* __restrict__ WhT,
    const float* __restrict__ s1, const float* __restrict__ s2,
    float* __restrict__ num_ws, float* __restrict__ den_ws)
{
    __shared__ u16 wht_lds[256 * 64];   // swizzled [n][kchunk^(n&7)], 32 KB
    __shared__ u16 p_lds[64 * 64];      // swizzled, 8 KB
    __shared__ float den_lds[64];

    const int t = threadIdx.x, lane = t & 63, w = t >> 6;
    const int q = lane >> 4, ln = lane & 15;
    const int b = blockIdx.z, split = blockIdx.y;
    const int i0 = blockIdx.x * 64;

    const int* adjb = b ? adj_d : adj_n;
    const u16* whtB = WhT + ((size_t)b << 20);
    const float* s1b = s1 + b * N_NODES;
    const float* s2b = s2 + b * N_NODES;

    const int pr = t >> 3;              // P row 0..31 (also handles pr+32)
    const int cw = t & 7;               // P k-chunk 0..7
    const int pc = cw * 8;
    const float s1v0 = s1b[i0 + pr];
    const float s1v1 = s1b[i0 + pr + 32];
    const size_t arow0 = (size_t)(i0 + pr) * N_NODES + pc;
    const size_t arow1 = arow0 + (size_t)32 * N_NODES;

    if (t < 64) den_lds[t] = 0.f;

    f32x4 acc[4][4];
    #pragma unroll
    for (int mt = 0; mt < 4; ++mt)
        #pragma unroll
        for (int nt = 0; nt < 4; ++nt) acc[mt][nt] = (f32x4){0.f, 0.f, 0.f, 0.f};

    const int jbase = split * (N_NODES / NSPLIT);
    int4 a00_pf = *(const int4*)&adjb[arow0 + jbase];
    int4 a01_pf = *(const int4*)&adjb[arow0 + jbase + 4];
    int4 a10_pf = *(const int4*)&adjb[arow1 + jbase];
    int4 a11_pf = *(const int4*)&adjb[arow1 + jbase + 4];
    float4 sv0_pf = *(const float4*)&s2b[jbase + pc];
    float4 sv1_pf = *(const float4*)&s2b[jbase + pc + 4];

    for (int jt = 0; jt < NTILES; ++jt) {
        const int j0 = jbase + jt * 64;
        __syncthreads();
        #pragma unroll
        for (int it = 0; it < 8; ++it) {   // stage 256n x 64j WhT tile
            int chunk = it * 256 + t;
            int n = chunk >> 3, kc = chunk & 7;
            const u16* g = whtB + (size_t)n * N_NODES + j0 + ((kc ^ (n & 7)) * 8);
            u16* l = wht_lds + (it * 256 + w * 64) * 8;
            __builtin_amdgcn_global_load_lds(
                (const __attribute__((address_space(1))) void*)g,
                (__attribute__((address_space(3))) void*)l, 16, 0, 0);
        }
        int4 a00 = a00_pf, a01 = a01_pf, a10 = a10_pf, a11 = a11_pf;
        float4 sv0 = sv0_pf, sv1 = sv1_pf;
        if (jt < NTILES - 1) {             // prefetch next tile (consumed ~1 tile later)
            const int jn = j0 + 64;
            a00_pf = *(const int4*)&adjb[arow0 + jn];
            a01_pf = *(const int4*)&adjb[arow0 + jn + 4];
            a10_pf = *(const int4*)&adjb[arow1 + jn];
            a11_pf = *(const int4*)&adjb[arow1 + jn + 4];
            sv0_pf = *(const float4*)&s2b[jn + pc];
            sv1_pf = *(const float4*)&s2b[jn + pc + 4];
        }
        int v0[8] = {a00.x, a00.y, a00.z, a00.w, a01.x, a01.y, a01.z, a01.w};
        int v1[8] = {a10.x, a10.y, a10.z, a10.w, a11.x, a11.y, a11.z, a11.w};
        float svf[8] = {sv0.x, sv0.y, sv0.z, sv0.w, sv1.x, sv1.y, sv1.z, sv1.w};
        float d0 = 0.f, d1 = 0.f;
        u16x8 pk0, pk1;
        #pragma unroll
        for (int jj = 0; jj < 8; ++jj) {
            float sv = svf[jj];
            float x0 = s1v0 + sv, x1 = s1v1 + sv;
            float p0 = (v0[jj] > 0) ? __expf(fmaxf(x0, 0.2f * x0)) : 0.f;
            float p1 = (v1[jj] > 0) ? __expf(fmaxf(x1, 0.2f * x1)) : 0.f;
            d0 += p0; d1 += p1;
            pk0[jj] = f2b(p0); pk1[jj] = f2b(p1);
        }
        d0 += __shfl_down(d0, 4, 8); d1 += __shfl_down(d1, 4, 8);
        d0 += __shfl_down(d0, 2, 8); d1 += __shfl_down(d1, 2, 8);
        d0 += __shfl_down(d0, 1, 8); d1 += __shfl_down(d1, 1, 8);
        if ((t & 7) == 0) { den_lds[pr] += d0; den_lds[pr + 32] += d1; }
        int swp = ((cw ^ (pr & 7)) * 8);
        *(u16x8*)&p_lds[pr * 64 + swp] = pk0;
        *(u16x8*)&p_lds[(pr + 32) * 64 + swp] = pk1;
        __syncthreads();
        #pragma unroll
        for (int ks = 0; ks < 2; ++ks) {
            int sw = ((ks * 4 + q) ^ (ln & 7)) * 8;
            bf16x8s af[4];
            #pragma unroll
            for (int mt = 0; mt < 4; ++mt)
                af[mt] = *(const bf16x8s*)&p_lds[(mt * 16 + ln) * 64 + sw];
            #pragma unroll
            for (int nt = 0; nt < 4; ++nt) {
                bf16x8s bfv = *(const bf16x8s*)&wht_lds[(w * 64 + nt * 16 + ln) * 64 + sw];
                #pragma unroll
                for (int mt = 0; mt < 4; ++mt)
                    acc[mt][nt] = __builtin_amdgcn_mfma_f32_16x16x32_bf16(af[mt], bfv, acc[mt][nt], 0, 0, 0);
            }
        }
    }
    const size_t pbase = (size_t)(b * NSPLIT + split) * N_NODES;
    #pragma unroll
    for (int mt = 0; mt < 4; ++mt)
        #pragma unroll
        for (int r = 0; r < 4; ++r) {
            int row = mt * 16 + q * 4 + r;
            #pragma unroll
            for (int nt = 0; nt < 4; ++nt)
                num_ws[(pbase + i0 + row) * FOUT + w * 64 + nt * 16 + ln] = acc[mt][nt][r];
        }
    if (t < 64) den_ws[pbase + i0 + t] = den_lds[t];
}

// ---------------------------------------------------------------------------
// reduce: sum splits, elu(num/den), merge branches.
// ---------------------------------------------------------------------------
__global__ __launch_bounds__(256) void reduce_kernel(
    const float* __restrict__ num_ws, const float* __restrict__ den_ws,
    float* __restrict__ out)
{
    int gid = blockIdx.x * 256 + threadIdx.x;
    int i = gid >> 6;
    int f4 = (gid & 63) * 4;
    float4 o = {0.f, 0.f, 0.f, 0.f};
    #pragma unroll
    for (int b = 0; b < 2; ++b) {
        float4 num = {0.f, 0.f, 0.f, 0.f};
        float den = 0.f;
        #pragma unroll
        for (int s = 0; s < NSPLIT; ++s) {
            const float4 v = *(const float4*)&num_ws[((size_t)(b * NSPLIT + s) * N_NODES + i) * FOUT + f4];
            num.x += v.x; num.y += v.y; num.z += v.z; num.w += v.w;
            den += den_ws[(size_t)(b * NSPLIT + s) * N_NODES + i];
        }
        float inv = 1.0f / den;
        float e0 = num.x * inv, e1 = num.y * inv, e2 = num.z * inv, e3 = num.w * inv;
        o.x += (e0 > 0.f) ? e0 : expm1f(e0);
        o.y += (e1 > 0.f) ? e1 : expm1f(e1);
        o.z += (e2 > 0.f) ? e2 : expm1f(e2);
        o.w += (e3 > 0.f) ? e3 : expm1f(e3);
    }
    *(float4*)&out[(size_t)i * FOUT + f4] = o;
}

extern "C" void kernel_launch(void* const* d_in, const int* in_sizes, int n_in,
                              void* d_out, int out_size, void* d_ws, size_t ws_size,
                              hipStream_t stream) {
    const float* h    = (const float*)d_in[0];
    const int*   adjn = (const int*)d_in[1];
    const int*   adjd = (const int*)d_in[2];
    const float* Wn   = (const float*)d_in[4];
    const float* a1n  = (const float*)d_in[5];
    const float* a2n  = (const float*)d_in[6];
    const float* Wd   = (const float*)d_in[7];
    const float* a1d  = (const float*)d_in[8];
    const float* a2d  = (const float*)d_in[9];

    char* ws = (char*)d_ws;
    // [0,4M): WhT   [4M,8M): (free)   [8M,8M+192K): s1,s2,den
    // [8.25M,12.25M): hb   [12.25M,12.75M): WTb   (dead after wh_gemm)
    // [8.25M,40.25M): num  (overlays hb/WTb; written by attn after wh_gemm)
    u16*  WhT  = (u16*)ws;
    float* s1  = (float*)(ws + ((size_t)8 << 20));
    float* s2  = s1 + 2 * N_NODES;
    float* den = s2 + 2 * N_NODES;
    u16*  hb   = (u16*)(ws + ((size_t)8 << 20) + ((size_t)256 << 10));
    u16*  WTb  = (u16*)(ws + ((size_t)12 << 20) + ((size_t)256 << 10));
    float* num = (float*)(ws + ((size_t)8 << 20) + ((size_t)256 << 10));

    prep_kernel<<<1089, 256, 0, stream>>>(h, Wn, Wd, hb, WTb, s1);
    wh_gemm_kernel<<<dim3(64, 4, 2), 256, 0, stream>>>(hb, WTb, a1n, a2n, a1d, a2d, WhT, s1, s2);
    attn_kernel<<<dim3(64, NSPLIT, 2), 256, 0, stream>>>(adjn, adjd, WhT, s1, s2, num, den);
    reduce_kernel<<<1024, 256, 0, stream>>>(num, den, (float*)d_out);
}